// Round 11
// baseline (243.883 us; speedup 1.0000x reference)
//
#include <hip/hip_runtime.h>
#include <math.h>

#define BB 2
#define SS 2048
#define DD 1024
#define HH 16
#define DHD 64
#define N3 3072
#define LN_EPS 1e-5f

#define PLANE (BB*HH*SS*DHD)   // 4194304 elements per q/k/v plane

typedef __attribute__((ext_vector_type(8))) short bf16x8;
typedef __attribute__((ext_vector_type(4))) float f32x4;
typedef __attribute__((ext_vector_type(16))) float f32x16;
typedef unsigned int u32;
typedef unsigned short ushort_t;

// fp32 -> bf16 round-to-nearest-even (finite inputs only)
static __device__ __forceinline__ short f2bf(float f) {
  union { float f; unsigned u; } a;
  a.f = f;
  unsigned r = a.u + 0x7fffu + ((a.u >> 16) & 1u);
  return (short)(r >> 16);
}

static __device__ __forceinline__ u32 fbits(float f) {
  union { float f; u32 u; } a; a.f = f; return a.u;
}

// raw v_exp_f32 (2^x); avoids libm exp2f range-fixup bloat
static __device__ __forceinline__ float ex2(float x) {
  float r;
  asm("v_exp_f32 %0, %1" : "=v"(r) : "v"(x));
  return r;
}

// pack two f32 -> one u32 of 2 bf16 (round-half-up), lo at low 16
static __device__ __forceinline__ u32 pkbf(float lo, float hi) {
  return __builtin_amdgcn_perm(fbits(hi) + 0x8000u, fbits(lo) + 0x8000u,
                               0x07060302u);
}

// async global->LDS, 16 bytes per lane; lds dest = base + lane*16 (wave-uniform base)
static __device__ __forceinline__ void gload_lds16(const void* g, void* l) {
  __builtin_amdgcn_global_load_lds(
      (const __attribute__((address_space(1))) u32*)g,
      (__attribute__((address_space(3))) u32*)l, 16, 0, 0);
}

// ---------------------------------------------------------------------------
// Fused prep kernel (R17-verified): x cast + weight transposes + vectorized
// mask bit-pack (int4 loads, shfl_xor tree; word w = elems 32w..32w+31).
// ---------------------------------------------------------------------------
#define PREP_CONV_B   2048
#define PREP_TA_B     768     // (3072/64)*(1024/64)
#define PREP_TO_B     256     // (1024/64)*(1024/64)
#define PREP_PACK_B   8192    // BB*SS*SS/(256*4)
#define PREP_TOTAL_B  (PREP_CONV_B + PREP_TA_B + PREP_TO_B + PREP_PACK_B)

__global__ __launch_bounds__(256) void prep_kernel(
    const float* __restrict__ x, ushort_t* __restrict__ xb,
    const float* __restrict__ Wa, ushort_t* __restrict__ watt,
    const float* __restrict__ Wo, ushort_t* __restrict__ wot,
    const int* __restrict__ mask, u32* __restrict__ bits) {
  __shared__ float tile[64][65];
  const int tid = threadIdx.x;
  const int bid = blockIdx.x;

  if (bid < PREP_CONV_B) {
    int i = (bid * 256 + tid) * 8;
    float4 a = *(const float4*)&x[i];
    float4 b = *(const float4*)&x[i + 4];
    short s[8] = {f2bf(a.x), f2bf(a.y), f2bf(a.z), f2bf(a.w),
                  f2bf(b.x), f2bf(b.y), f2bf(b.z), f2bf(b.w)};
    *(bf16x8*)&xb[i] = *(bf16x8*)s;
    return;
  }
  if (bid < PREP_CONV_B + PREP_TA_B + PREP_TO_B) {
    const float* W; ushort_t* Wt; int K, N, nb, kb;
    if (bid < PREP_CONV_B + PREP_TA_B) {
      int idx = bid - PREP_CONV_B;
      W = Wa; Wt = watt; K = DD; N = N3;
      nb = (idx % 48) * 64; kb = (idx / 48) * 64;
    } else {
      int idx = bid - PREP_CONV_B - PREP_TA_B;
      W = Wo; Wt = wot; K = DD; N = DD;
      nb = (idx % 16) * 64; kb = (idx / 16) * 64;
    }
    #pragma unroll
    for (int i = 0; i < 4; ++i) {
      int idx = tid + i * 256;
      int r = idx >> 4, c = (idx & 15) * 4;
      float4 v = *(const float4*)&W[(size_t)(kb + r) * N + nb + c];
      tile[r][c] = v.x; tile[r][c + 1] = v.y;
      tile[r][c + 2] = v.z; tile[r][c + 3] = v.w;
    }
    __syncthreads();
    #pragma unroll
    for (int i = 0; i < 4; ++i) {
      int idx = tid + i * 256;
      int n = idx >> 4, k = (idx & 15) * 4;
      short4 s;
      s.x = f2bf(tile[k][n]); s.y = f2bf(tile[k + 1][n]);
      s.z = f2bf(tile[k + 2][n]); s.w = f2bf(tile[k + 3][n]);
      *(short4*)&Wt[(size_t)(nb + n) * K + kb + k] = s;
    }
    return;
  }
  {
    // mask bit-pack: thread handles 4 consecutive ints (16B load)
    size_t idx = (size_t)(bid - PREP_CONV_B - PREP_TA_B - PREP_TO_B) * 256 + tid;
    size_t g4 = idx * 4;                       // element base, %4==0
    int4 m = *(const int4*)&mask[g4];
    u32 v = (m.x != 0 ? 1u : 0u) | (m.y != 0 ? 2u : 0u)
          | (m.z != 0 ? 4u : 0u) | (m.w != 0 ? 8u : 0u);
    v |= (u32)__shfl_xor((int)v, 1) << 4;      // even lanes: 8 bits
    v |= (u32)__shfl_xor((int)v, 2) << 8;      // lanes %4==0: 16 bits
    v |= (u32)__shfl_xor((int)v, 4) << 16;     // lanes %8==0: 32 bits
    if ((tid & 7) == 0) bits[g4 >> 5] = v;     // word w = elems 32w..32w+31
  }
}

// ===========================================================================
// m97-style bf16 MFMA GEMM core (R2-verified): C[128x128] = A[128xK]*Bt^T
// Default block order (R16 lesson: NBX%8==0 already gives B-col->XCD L2
// affinity; swizzling broke it). As/Bs 16B-aligned for epilogue reuse.
// ===========================================================================
#define GEMM_MAIN(Aptr, Btptr, Kdim)                                          \
  __shared__ __align__(16) ushort_t As[128 * 64];                             \
  __shared__ __align__(16) ushort_t Bs[128 * 64];                             \
  const int tid = threadIdx.x;                                                \
  const int wave = tid >> 6, lane = tid & 63;                                 \
  const int lane16 = lane & 15, quad = lane >> 4;                             \
  const int wm = wave & 1, wn = wave >> 1;                                    \
  const int bm = blockIdx.y * 128, bn = blockIdx.x * 128;                     \
  const int srow = lane >> 3;                                                 \
  const int sg = (lane & 7) ^ srow;                                           \
  f32x4 acc[4][4];                                                            \
  _Pragma("unroll") for (int i = 0; i < 4; ++i)                               \
    _Pragma("unroll") for (int j = 0; j < 4; ++j)                             \
      acc[i][j] = (f32x4){0.f, 0.f, 0.f, 0.f};                                \
  const ushort_t* agp[4];                                                     \
  const ushort_t* bgp[4];                                                     \
  _Pragma("unroll") for (int i = 0; i < 4; ++i) {                             \
    int seg = wave * 4 + i;                                                   \
    int r = seg * 8 + srow;                                                   \
    agp[i] = Aptr + (size_t)(bm + r) * Kdim + sg * 8;                         \
    bgp[i] = Btptr + (size_t)(bn + r) * Kdim + sg * 8;                        \
  }                                                                           \
  for (int k0 = 0; k0 < Kdim; k0 += 64) {                                     \
    _Pragma("unroll") for (int i = 0; i < 4; ++i) {                           \
      int seg = wave * 4 + i;                                                 \
      gload_lds16(agp[i] + k0, &As[seg * 512]);                               \
      gload_lds16(bgp[i] + k0, &Bs[seg * 512]);                               \
    }                                                                         \
    __syncthreads();                                                          \
    _Pragma("unroll") for (int ks = 0; ks < 2; ++ks) {                        \
      bf16x8 af[4], bfr[4];                                                   \
      _Pragma("unroll") for (int mt = 0; mt < 4; ++mt) {                      \
        int ra = wm * 64 + mt * 16 + lane16;                                  \
        int kc = ks * 4 + quad;                                               \
        af[mt] = *(const bf16x8*)&As[ra * 64 + ((kc ^ (ra & 7)) * 8)];        \
      }                                                                       \
      _Pragma("unroll") for (int nt = 0; nt < 4; ++nt) {                      \
        int rb = wn * 64 + nt * 16 + lane16;                                  \
        int kc = ks * 4 + quad;                                               \
        bfr[nt] = *(const bf16x8*)&Bs[rb * 64 + ((kc ^ (rb & 7)) * 8)];       \
      }                                                                       \
      _Pragma("unroll") for (int mt = 0; mt < 4; ++mt)                        \
        _Pragma("unroll") for (int nt = 0; nt < 4; ++nt)                      \
          acc[mt][nt] = __builtin_amdgcn_mfma_f32_16x16x32_bf16(              \
              af[mt], bfr[nt], acc[mt][nt], 0, 0, 0);                         \
    }                                                                         \
    __syncthreads();                                                          \
  }

// ---------------------------------------------------------------------------
// GEMM 1: qkv -> bf16 head-major q/k [B,H,S,DH]; V^T [B,H,DH,S] directly.
// R18: V-block (which==2, block-uniform) writes go through a per-wave LDS
// transpose (reusing As, dead after GEMM_MAIN's final barrier; no cross-wave
// sharing -> no barriers) so each thread issues 8 coalesced b128 stores
// instead of 64 scattered 2B stores at 4KB stride.
// ---------------------------------------------------------------------------
__global__ __launch_bounds__(256) void gemm_qkv_mfma(
    const ushort_t* __restrict__ A, const ushort_t* __restrict__ Bt,
    const float* __restrict__ bias, ushort_t* __restrict__ qkvh,
    ushort_t* __restrict__ vtb) {
  GEMM_MAIN(A, Bt, DD)
  const int whichb = bn >> 10;               // block-uniform (1024 % 128 == 0)
  if (whichb == 2) {
    // per-wave slice: 16 d-rows x 72 shorts (144B stride: 16B-aligned, ~2-way
    // write banks). 4 waves x 1152 shorts = 4608 <= As's 8192.
    ushort_t* ws_ = As + wave * 1152;
    const int bb = bm >> 11;
    const int ssb = (bm & 2047) + wm * 64;   // wave's 64-row ss base
    const int head2 = ((bn & 1023) >> 6) + wn;
    const int dl = lane >> 2, s16 = (lane & 3) * 16;
    ushort_t* dst0 = vtb + ((size_t)(bb * HH + head2) * DHD) * SS + ssb + s16;
    #pragma unroll
    for (int nt = 0; nt < 4; ++nt) {
      float bv = bias[bn + wn * 64 + nt * 16 + lane16];
      #pragma unroll
      for (int mt = 0; mt < 4; ++mt) {
        #pragma unroll
        for (int reg = 0; reg < 4; ++reg) {
          ws_[lane16 * 72 + mt * 16 + quad * 4 + reg] =
              (ushort_t)f2bf(acc[mt][nt][reg] + bv);
        }
      }
      // same-wave cross-lane LDS: compiler-inserted lgkmcnt orders this
      bf16x8 v0 = *(const bf16x8*)&ws_[dl * 72 + s16];
      bf16x8 v1 = *(const bf16x8*)&ws_[dl * 72 + s16 + 8];
      ushort_t* dst = dst0 + (size_t)(nt * 16 + dl) * SS;
      *(bf16x8*)&dst[0] = v0;
      *(bf16x8*)&dst[8] = v1;
    }
  } else {
    ushort_t* plane = qkvh + (size_t)whichb * PLANE;
    #pragma unroll
    for (int nt = 0; nt < 4; ++nt) {
      int col = bn + wn * 64 + nt * 16 + lane16;
      int hcol = col & 1023;
      int head = hcol >> 6, d = hcol & 63;
      float bv = bias[col];
      #pragma unroll
      for (int mt = 0; mt < 4; ++mt) {
        #pragma unroll
        for (int reg = 0; reg < 4; ++reg) {
          int row = bm + wm * 64 + mt * 16 + quad * 4 + reg;
          int bb = row >> 11, ss = row & (SS - 1);
          plane[((size_t)(bb * HH + head) * SS + ss) * DHD + d] =
              (ushort_t)f2bf(acc[mt][nt][reg] + bv);
        }
      }
    }
  }
}

// ---------------------------------------------------------------------------
// GEMM 2 (R2-verified): y = x + attnb @ W_out + b_out -> fp32 d_out
// ---------------------------------------------------------------------------
__global__ __launch_bounds__(256) void gemm_proj_mfma(
    const ushort_t* __restrict__ A, const ushort_t* __restrict__ Bt,
    const float* __restrict__ bias, const float* __restrict__ xres,
    float* __restrict__ Y) {
  GEMM_MAIN(A, Bt, DD)
  #pragma unroll
  for (int nt = 0; nt < 4; ++nt) {
    int col = bn + wn * 64 + nt * 16 + lane16;
    float bv = bias[col];
    #pragma unroll
    for (int mt = 0; mt < 4; ++mt) {
      #pragma unroll
      for (int reg = 0; reg < 4; ++reg) {
        int row = bm + wm * 64 + mt * 16 + quad * 4 + reg;
        Y[(size_t)row * DD + col] =
            acc[mt][nt][reg] + bv + xres[(size_t)row * DD + col];
      }
    }
  }
}

// ---------------------------------------------------------------------------
// bf16 MFMA flash attention: EXACT R12 body (58.9us verified; no spills at
// VGPR 64 + 32 acc). R13/R14/R15: ANY accumulator growth spills ~9MB to
// scratch. Do not grow state here. Bank-conflict 4.19M = intrinsic b128
// wave64 cost (4 cyc/read, m134) -- not a layout bug, not fixable.
// ---------------------------------------------------------------------------
__global__ __launch_bounds__(512, 4) void attn_mfma_kernel(
    const ushort_t* __restrict__ qh, const ushort_t* __restrict__ kh,
    const ushort_t* __restrict__ vt, const u32* __restrict__ mbits,
    ushort_t* __restrict__ attn_out) {
  __shared__ __align__(16) ushort_t S[2][2][2][4096]; // [dbuf][K/V][khalf]

  const int tid = threadIdx.x;
  const int wave = tid >> 6, lane = tid & 63;
  const int l31 = lane & 31, hi = lane >> 5;

  const int bh = blockIdx.x & 31;          // b*16 + h
  const int qt = blockIdx.x >> 5;          // q tile of 128 (16 tiles)
  const int bbi = bh >> 4, hhi = bh & 15;
  const size_t head_base = (size_t)bh * SS * DHD;
  const int wq = wave & 3, khx = wave >> 2;
  const int q32 = qt * 128 + wq * 32;
  const int qrow = q32 + l31;              // this lane's q-row (scores + mask)

  // Q B-fragments, pre-scaled by log2(e)/sqrt(DH): qf[dk] holds row=qrow,
  // d = dk*16 + hi*8 .. +8  (32x32x16 B layout: col=lane&31, k=(lane>>5)*8+e)
  bf16x8 qf[4];
  {
    const float kScale = 0.125f * 1.44269504f;
    const ushort_t* qsrc = &qh[head_base + (size_t)qrow * DHD + hi * 8];
    #pragma unroll
    for (int dk = 0; dk < 4; ++dk) {
      bf16x8 r = *(const bf16x8*)&qsrc[dk * 16];
      #pragma unroll
      for (int e = 0; e < 8; ++e) {
        union { u32 u; float f; } c;
        c.u = ((u32)(ushort_t)r[e]) << 16;
        c.f *= kScale;
        r[e] = f2bf(c.f);
      }
      qf[dk] = r;
    }
  }

  f32x16 acc0, acc1;                       // O[q][d]: d = dt*32 + l31
  #pragma unroll
  for (int e = 0; e < 16; ++e) { acc0[e] = 0.f; acc1[e] = 0.f; }
  float lsum = 0.f;                        // sum of exps, all for q = qrow

  // mask words for this q-row, this k-half (32 u32 per half)
  const u32* mrow = mbits + ((size_t)(bbi * SS) + qrow) * 64 + khx * 32;

  // staging: 512 threads stage 4 tiles (K half0/1, V half0/1) of 512 chunks.
  // thread -> chunk (r = tid>>3, c = tid&7); source chunk pre-swizzled.
  const int sr = tid >> 3;
  const int scsrc = (tid & 7) ^ (sr & 7);
  const ushort_t* kst0 = kh + head_base + (size_t)sr * DHD + scsrc * 8;
  const ushort_t* vst0 = vt + head_base + (size_t)sr * SS + scsrc * 8;
  const int sdst = wave * 512;             // wave-uniform LDS base (shorts)

#define ATTN_STAGE(buf, t)                                                    \
  gload_lds16(kst0 + (size_t)(t) * 64 * DHD, &S[buf][0][0][sdst]);            \
  gload_lds16(kst0 + (size_t)(1024 + (t) * 64) * DHD, &S[buf][0][1][sdst]);   \
  gload_lds16(vst0 + (t) * 64, &S[buf][1][0][sdst]);                          \
  gload_lds16(vst0 + 1024 + (t) * 64, &S[buf][1][1][sdst]);

  ATTN_STAGE(0, 0);
  uint2 mcur = *(const uint2*)mrow;
  __syncthreads();

  const int NT = 16;                       // 1024 k per half / 64
  for (int t = 0; t < NT; ++t) {
    const int cur = t & 1;
    uint2 mnext = mcur;
    if (t + 1 < NT) {
      ATTN_STAGE(cur ^ 1, t + 1);
      mnext = *(const uint2*)&mrow[(t + 1) * 2];
    }

    const ushort_t* Kb = &S[cur][0][khx][0];
    const ushort_t* Vb = &S[cur][1][khx][0];

    // S^T = K.Q^T: two 32-k sub-tiles; C col = l31 = q, row = k pattern
    f32x16 s0, s1;
    #pragma unroll
    for (int e = 0; e < 16; ++e) { s0[e] = 0.f; s1[e] = 0.f; }
    #pragma unroll
    for (int dk = 0; dk < 4; ++dk) {
      const int c = 2 * dk + hi;
      const int r0 = l31;
      bf16x8 kf0 = *(const bf16x8*)&Kb[r0 * 64 + ((c ^ (r0 & 7)) * 8)];
      s0 = __builtin_amdgcn_mfma_f32_32x32x16_bf16(kf0, qf[dk], s0, 0, 0, 0);
      const int r1 = 32 + l31;
      bf16x8 kf1 = *(const bf16x8*)&Kb[r1 * 64 + ((c ^ (r1 & 7)) * 8)];
      s1 = __builtin_amdgcn_mfma_f32_32x32x16_bf16(kf1, qf[dk], s1, 0, 0, 0);
    }

    // per K=16 slice: mask+exp (k = 8g + 4hi + r), pack, permlane-swap to
    // build PV A-frag (row=q=l31, k=(hi)*8+e), then PV MFMA
    #pragma unroll
    for (int ks16 = 0; ks16 < 4; ++ks16) {
      const int ksub = ks16 >> 1;          // which 32-k sub-tile
      const int g0 = (ks16 & 1) * 2;       // first 8-k block within sub-tile
      const f32x16 sv = ksub ? s1 : s0;
      const u32 w32 = ksub ? mcur.y : mcur.x;
      const u32 na = w32 >> (g0 * 8 + hi * 4);
      const u32 nb = w32 >> (g0 * 8 + 8 + hi * 4);
      float e0 = (na & 1u) ? 0.f : ex2(sv[g0 * 4 + 0]);
      float e1 = (na & 2u) ? 0.f : ex2(sv[g0 * 4 + 1]);
      float e2 = (na & 4u) ? 0.f : ex2(sv[g0 * 4 + 2]);
      float e3 = (na & 8u) ? 0.f : ex2(sv[g0 * 4 + 3]);
      float f0 = (nb & 1u) ? 0.f : ex2(sv[g0 * 4 + 4]);
      float f1 = (nb & 2u) ? 0.f : ex2(sv[g0 * 4 + 5]);
      float f2 = (nb & 4u) ? 0.f : ex2(sv[g0 * 4 + 6]);
      float f3 = (nb & 8u) ? 0.f : ex2(sv[g0 * 4 + 7]);
      lsum += ((e0 + e1) + (e2 + e3)) + ((f0 + f1) + (f2 + f3));
      u32 a0 = pkbf(e0, e1), a1 = pkbf(e2, e3);
      u32 b0 = pkbf(f0, f1), b1 = pkbf(f2, f3);
      // swap: a' = {a_lo | b_lo from partner}, b' = {a_hi from partner | b_hi}
      asm("v_permlane32_swap_b32 %0, %1" : "+v"(a0), "+v"(b0));
      asm("v_permlane32_swap_b32 %0, %1" : "+v"(a1), "+v"(b1));
      union { u32 w[4]; bf16x8 v; } pfu;
      pfu.w[0] = a0; pfu.w[1] = a1; pfu.w[2] = b0; pfu.w[3] = b1;
      {
        const int rv0 = l31;
        const int cv = 2 * ks16 + hi;
        bf16x8 vf0 = *(const bf16x8*)&Vb[rv0 * 64 + ((cv ^ (rv0 & 7)) * 8)];
        acc0 = __builtin_amdgcn_mfma_f32_32x32x16_bf16(pfu.v, vf0, acc0, 0, 0, 0);
        const int rv1 = 32 + l31;
        bf16x8 vf1 = *(const bf16x8*)&Vb[rv1 * 64 + ((cv ^ (rv1 & 7)) * 8)];
        acc1 = __builtin_amdgcn_mfma_f32_32x32x16_bf16(pfu.v, vf1, acc1, 0, 0, 0);
      }
    }

    mcur = mnext;
    __syncthreads();   // drains gloads; separates buffer reuse
  }
#undef ATTN_STAGE

  // ---- merge k-halves + l transpose through LDS (staging bufs are dead) ----
  // stride 33 f32: bank = (lane*33 + e) % 32 = (lane + e) % 32 -> conflict-free
  float* mbuf = (float*)&S[0][0][0][0];            // [4][64][33] f32 = 33792 B
  float* lbuf = mbuf + 4 * 64 * 33;                // [khW][wq][hiW][32] = 2 KB
  lbuf[((khx * 4 + wq) * 2 + hi) * 32 + l31] = lsum;
  if (khx == 1) {
    float* dst = mbuf + (size_t)(wq * 64 + lane) * 33;
    #pragma unroll
    for (int e = 0; e < 16; ++e) { dst[e] = acc0[e]; dst[16 + e] = acc1[e]; }
  }
  __syncthreads();
  if (khx == 0) {
    const float* src = mbuf + (size_t)(wq * 64 + lane) * 33;
    #pragma unroll
    for (int e = 0; e < 16; ++e) { acc0[e] += src[e]; acc1[e] += src[16 + e]; }
    #pragma unroll
    for (int reg = 0; reg < 16; ++reg) {
      const int kq = (reg & 3) + 8 * (reg >> 2) + 4 * hi;   // q offset in 32
      float lq = lbuf[((0 * 4 + wq) * 2 + 0) * 32 + kq]
               + lbuf[((0 * 4 + wq) * 2 + 1) * 32 + kq]
               + lbuf[((1 * 4 + wq) * 2 + 0) * 32 + kq]
               + lbuf[((1 * 4 + wq) * 2 + 1) * 32 + kq];
      const float inv = 1.0f / lq;
      ushort_t* orow = &attn_out[((size_t)(bbi * SS) + q32 + kq) * DD
                                 + hhi * DHD];
      orow[l31] = (ushort_t)f2bf(acc0[reg] * inv);
      orow[32 + l31] = (ushort_t)f2bf(acc1[reg] * inv);
    }
  }
}

// ---------------------------------------------------------------------------
// in-place LayerNorm over D=1024 per row
// ---------------------------------------------------------------------------
__global__ __launch_bounds__(256) void ln_kernel(
    float* __restrict__ Y, const float* __restrict__ g,
    const float* __restrict__ bta) {
  const int r = blockIdx.x;
  const int tid = threadIdx.x;
  float4 v = *(const float4*)&Y[(size_t)r * DD + tid * 4];
  float sum = v.x + v.y + v.z + v.w;
  float sq = v.x * v.x + v.y * v.y + v.z * v.z + v.w * v.w;
  #pragma unroll
  for (int off = 32; off; off >>= 1) {
    sum += __shfl_down(sum, off);
    sq += __shfl_down(sq, off);
  }
  __shared__ float ps[4], pq[4];
  __shared__ float mu_s, rs_s;
  const int wave = tid >> 6;
  if ((tid & 63) == 0) { ps[wave] = sum; pq[wave] = sq; }
  __syncthreads();
  if (tid == 0) {
    float s = ps[0] + ps[1] + ps[2] + ps[3];
    float qq = pq[0] + pq[1] + pq[2] + pq[3];
    float mu = s * (1.0f / DD);
    float var = qq * (1.0f / DD) - mu * mu;
    mu_s = mu;
    rs_s = rsqrtf(var + LN_EPS);
  }
  __syncthreads();
  const float mu = mu_s, rs = rs_s;
  float4 g4 = *(const float4*)&g[tid * 4];
  float4 b4 = *(const float4*)&bta[tid * 4];
  float4 ov;
  ov.x = (v.x - mu) * rs * g4.x + b4.x;
  ov.y = (v.y - mu) * rs * g4.y + b4.y;
  ov.z = (v.z - mu) * rs * g4.z + b4.z;
  ov.w = (v.w - mu) * rs * g4.w + b4.w;
  *(float4*)&Y[(size_t)r * DD + tid * 4] = ov;
}

// ---------------------------------------------------------------------------
extern "C" void kernel_launch(void* const* d_in, const int* in_sizes, int n_in,
                              void* d_out, int out_size, void* d_ws, size_t ws_size,
                              hipStream_t stream) {
  const float* x      = (const float*)d_in[0];
  const float* W_attn = (const float*)d_in[1];
  const float* b_attn = (const float*)d_in[2];
  const float* W_out  = (const float*)d_in[3];
  const float* b_out  = (const float*)d_in[4];
  const float* ln_g   = (const float*)d_in[5];
  const float* ln_b   = (const float*)d_in[6];
  const int*   mask   = (const int*)d_in[7];
  float* out = (float*)d_out;
  ushort_t* ws = (ushort_t*)d_ws;

  ushort_t* xb    = ws;                                   // [4096][1024] bf16
  ushort_t* watt  = xb + (size_t)BB * SS * DD;            // [3072][1024] W_attn^T
  ushort_t* wot   = watt + (size_t)N3 * DD;               // [1024][1024] W_out^T
  ushort_t* qh    = wot + (size_t)DD * DD;                // [B,H,S,DH] q plane
  ushort_t* kh    = qh + (size_t)PLANE;                   // [B,H,S,DH] k plane
  ushort_t* vtb   = kh + (size_t)PLANE;                   // [B,H,DH,S] V^T
  ushort_t* attnb = vtb + (size_t)PLANE;                  // [4096][1024]
  u32* mbits      = (u32*)(attnb + (size_t)BB * SS * DD); // 1 MB packed mask

  // 0) fused prep: x cast + both weight transposes + mask bit-pack
  prep_kernel<<<dim3(PREP_TOTAL_B), 256, 0, stream>>>(
      x, xb, W_attn, watt, W_out, wot, mask, mbits);

  // 1) QKV projection (bf16 MFMA) -> q/k head-major, V^T via LDS transpose
  gemm_qkv_mfma<<<dim3(N3 / 128, (BB * SS) / 128), 256, 0, stream>>>(
      xb, watt, b_attn, qh, vtb);
  // 2) bf16 MFMA flash attention (exact R12 body)
  attn_mfma_kernel<<<dim3(BB * HH * (SS / 128)), 512, 0, stream>>>(
      qh, kh, vtb, mbits, attnb);
  // 3) out projection + bias + residual (bf16 MFMA)
  gemm_proj_mfma<<<dim3(DD / 128, (BB * SS) / 128), 256, 0, stream>>>(
      attnb, wot, b_out, x, out);
  // 4) in-place LayerNorm
  ln_kernel<<<dim3(BB * SS), 256, 0, stream>>>(out, ln_g, ln_b);
}

// Round 12
// 228.793 us; speedup vs baseline: 1.0660x; 1.0660x over previous
//
#include <hip/hip_runtime.h>
#include <math.h>

#define BB 2
#define SS 2048
#define DD 1024
#define HH 16
#define DHD 64
#define N3 3072
#define LN_EPS 1e-5f

#define PLANE (BB*HH*SS*DHD)   // 4194304 elements per q/k/v plane

typedef __attribute__((ext_vector_type(8))) short bf16x8;
typedef __attribute__((ext_vector_type(4))) float f32x4;
typedef __attribute__((ext_vector_type(16))) float f32x16;
typedef unsigned int u32;
typedef unsigned short ushort_t;

// fp32 -> bf16 round-to-nearest-even (finite inputs only)
static __device__ __forceinline__ short f2bf(float f) {
  union { float f; unsigned u; } a;
  a.f = f;
  unsigned r = a.u + 0x7fffu + ((a.u >> 16) & 1u);
  return (short)(r >> 16);
}

static __device__ __forceinline__ u32 fbits(float f) {
  union { float f; u32 u; } a; a.f = f; return a.u;
}

// raw v_exp_f32 (2^x); avoids libm exp2f range-fixup bloat
static __device__ __forceinline__ float ex2(float x) {
  float r;
  asm("v_exp_f32 %0, %1" : "=v"(r) : "v"(x));
  return r;
}

// pack two f32 -> one u32 of 2 bf16 (round-half-up), lo at low 16
static __device__ __forceinline__ u32 pkbf(float lo, float hi) {
  return __builtin_amdgcn_perm(fbits(hi) + 0x8000u, fbits(lo) + 0x8000u,
                               0x07060302u);
}

// async global->LDS, 16 bytes per lane; lds dest = base + lane*16 (wave-uniform base)
static __device__ __forceinline__ void gload_lds16(const void* g, void* l) {
  __builtin_amdgcn_global_load_lds(
      (const __attribute__((address_space(1))) u32*)g,
      (__attribute__((address_space(3))) u32*)l, 16, 0, 0);
}

// ---------------------------------------------------------------------------
// Fused prep kernel (R17-verified): x cast + weight transposes + vectorized
// mask bit-pack (int4 loads, shfl_xor tree; word w = elems 32w..32w+31).
// ---------------------------------------------------------------------------
#define PREP_CONV_B   2048
#define PREP_TA_B     768     // (3072/64)*(1024/64)
#define PREP_TO_B     256     // (1024/64)*(1024/64)
#define PREP_PACK_B   8192    // BB*SS*SS/(256*4)
#define PREP_TOTAL_B  (PREP_CONV_B + PREP_TA_B + PREP_TO_B + PREP_PACK_B)

__global__ __launch_bounds__(256) void prep_kernel(
    const float* __restrict__ x, ushort_t* __restrict__ xb,
    const float* __restrict__ Wa, ushort_t* __restrict__ watt,
    const float* __restrict__ Wo, ushort_t* __restrict__ wot,
    const int* __restrict__ mask, u32* __restrict__ bits) {
  __shared__ float tile[64][65];
  const int tid = threadIdx.x;
  const int bid = blockIdx.x;

  if (bid < PREP_CONV_B) {
    int i = (bid * 256 + tid) * 8;
    float4 a = *(const float4*)&x[i];
    float4 b = *(const float4*)&x[i + 4];
    short s[8] = {f2bf(a.x), f2bf(a.y), f2bf(a.z), f2bf(a.w),
                  f2bf(b.x), f2bf(b.y), f2bf(b.z), f2bf(b.w)};
    *(bf16x8*)&xb[i] = *(bf16x8*)s;
    return;
  }
  if (bid < PREP_CONV_B + PREP_TA_B + PREP_TO_B) {
    const float* W; ushort_t* Wt; int K, N, nb, kb;
    if (bid < PREP_CONV_B + PREP_TA_B) {
      int idx = bid - PREP_CONV_B;
      W = Wa; Wt = watt; K = DD; N = N3;
      nb = (idx % 48) * 64; kb = (idx / 48) * 64;
    } else {
      int idx = bid - PREP_CONV_B - PREP_TA_B;
      W = Wo; Wt = wot; K = DD; N = DD;
      nb = (idx % 16) * 64; kb = (idx / 16) * 64;
    }
    #pragma unroll
    for (int i = 0; i < 4; ++i) {
      int idx = tid + i * 256;
      int r = idx >> 4, c = (idx & 15) * 4;
      float4 v = *(const float4*)&W[(size_t)(kb + r) * N + nb + c];
      tile[r][c] = v.x; tile[r][c + 1] = v.y;
      tile[r][c + 2] = v.z; tile[r][c + 3] = v.w;
    }
    __syncthreads();
    #pragma unroll
    for (int i = 0; i < 4; ++i) {
      int idx = tid + i * 256;
      int n = idx >> 4, k = (idx & 15) * 4;
      short4 s;
      s.x = f2bf(tile[k][n]); s.y = f2bf(tile[k + 1][n]);
      s.z = f2bf(tile[k + 2][n]); s.w = f2bf(tile[k + 3][n]);
      *(short4*)&Wt[(size_t)(nb + n) * K + kb + k] = s;
    }
    return;
  }
  {
    // mask bit-pack: thread handles 4 consecutive ints (16B load)
    size_t idx = (size_t)(bid - PREP_CONV_B - PREP_TA_B - PREP_TO_B) * 256 + tid;
    size_t g4 = idx * 4;                       // element base, %4==0
    int4 m = *(const int4*)&mask[g4];
    u32 v = (m.x != 0 ? 1u : 0u) | (m.y != 0 ? 2u : 0u)
          | (m.z != 0 ? 4u : 0u) | (m.w != 0 ? 8u : 0u);
    v |= (u32)__shfl_xor((int)v, 1) << 4;      // even lanes: 8 bits
    v |= (u32)__shfl_xor((int)v, 2) << 8;      // lanes %4==0: 16 bits
    v |= (u32)__shfl_xor((int)v, 4) << 16;     // lanes %8==0: 32 bits
    if ((tid & 7) == 0) bits[g4 >> 5] = v;     // word w = elems 32w..32w+31
  }
}

// ===========================================================================
// m97-style bf16 MFMA GEMM core (R2-verified): C[128x128] = A[128xK]*Bt^T
// Default block order (R16 lesson: NBX%8==0 already gives B-col->XCD L2
// affinity; swizzling broke it).
// ===========================================================================
#define GEMM_MAIN(Aptr, Btptr, Kdim)                                          \
  __shared__ ushort_t As[128 * 64];                                           \
  __shared__ ushort_t Bs[128 * 64];                                           \
  const int tid = threadIdx.x;                                                \
  const int wave = tid >> 6, lane = tid & 63;                                 \
  const int lane16 = lane & 15, quad = lane >> 4;                             \
  const int wm = wave & 1, wn = wave >> 1;                                    \
  const int bm = blockIdx.y * 128, bn = blockIdx.x * 128;                     \
  const int srow = lane >> 3;                                                 \
  const int sg = (lane & 7) ^ srow;                                           \
  f32x4 acc[4][4];                                                            \
  _Pragma("unroll") for (int i = 0; i < 4; ++i)                               \
    _Pragma("unroll") for (int j = 0; j < 4; ++j)                             \
      acc[i][j] = (f32x4){0.f, 0.f, 0.f, 0.f};                                \
  const ushort_t* agp[4];                                                     \
  const ushort_t* bgp[4];                                                     \
  _Pragma("unroll") for (int i = 0; i < 4; ++i) {                             \
    int seg = wave * 4 + i;                                                   \
    int r = seg * 8 + srow;                                                   \
    agp[i] = Aptr + (size_t)(bm + r) * Kdim + sg * 8;                         \
    bgp[i] = Btptr + (size_t)(bn + r) * Kdim + sg * 8;                        \
  }                                                                           \
  for (int k0 = 0; k0 < Kdim; k0 += 64) {                                     \
    _Pragma("unroll") for (int i = 0; i < 4; ++i) {                           \
      int seg = wave * 4 + i;                                                 \
      gload_lds16(agp[i] + k0, &As[seg * 512]);                               \
      gload_lds16(bgp[i] + k0, &Bs[seg * 512]);                               \
    }                                                                         \
    __syncthreads();                                                          \
    _Pragma("unroll") for (int ks = 0; ks < 2; ++ks) {                        \
      bf16x8 af[4], bfr[4];                                                   \
      _Pragma("unroll") for (int mt = 0; mt < 4; ++mt) {                      \
        int ra = wm * 64 + mt * 16 + lane16;                                  \
        int kc = ks * 4 + quad;                                               \
        af[mt] = *(const bf16x8*)&As[ra * 64 + ((kc ^ (ra & 7)) * 8)];        \
      }                                                                       \
      _Pragma("unroll") for (int nt = 0; nt < 4; ++nt) {                      \
        int rb = wn * 64 + nt * 16 + lane16;                                  \
        int kc = ks * 4 + quad;                                               \
        bfr[nt] = *(const bf16x8*)&Bs[rb * 64 + ((kc ^ (rb & 7)) * 8)];       \
      }                                                                       \
      _Pragma("unroll") for (int mt = 0; mt < 4; ++mt)                        \
        _Pragma("unroll") for (int nt = 0; nt < 4; ++nt)                      \
          acc[mt][nt] = __builtin_amdgcn_mfma_f32_16x16x32_bf16(              \
              af[mt], bfr[nt], acc[mt][nt], 0, 0, 0);                         \
    }                                                                         \
    __syncthreads();                                                          \
  }

// ---------------------------------------------------------------------------
// GEMM 1: qkv -> bf16 head-major q/k [B,H,S,DH]; V^T [B,H,DH,S] directly.
// R19: V-branch writes vectorized IN-REGISTER (no LDS -- R18's LDS transpose
// cost +15us): each thread's reg=0..3 are 4 consecutive ss rows for one d,
// so one short4 (8B) store per (nt,mt) replaces 4 scalar 2B stores.
// 64 -> 16 store instructions, 4x sector utilization. q/k path unchanged.
// ---------------------------------------------------------------------------
__global__ __launch_bounds__(256) void gemm_qkv_mfma(
    const ushort_t* __restrict__ A, const ushort_t* __restrict__ Bt,
    const float* __restrict__ bias, ushort_t* __restrict__ qkvh,
    ushort_t* __restrict__ vtb) {
  GEMM_MAIN(A, Bt, DD)
  #pragma unroll
  for (int nt = 0; nt < 4; ++nt) {
    int col = bn + wn * 64 + nt * 16 + lane16;
    int which = col >> 10, hcol = col & 1023;
    int head = hcol >> 6, d = hcol & 63;
    float bv = bias[col];
    if (which == 2) {
      // rows bm..bm+127 never cross a 2048 boundary (128 | 2048)
      const int bb = bm >> 11;
      const int ssb = (bm & 2047) + wm * 64 + quad * 4;
      ushort_t* vrow = vtb + ((size_t)(bb * HH + head) * DHD + d) * SS;
      #pragma unroll
      for (int mt = 0; mt < 4; ++mt) {
        short4 s;
        s.x = f2bf(acc[mt][nt][0] + bv);
        s.y = f2bf(acc[mt][nt][1] + bv);
        s.z = f2bf(acc[mt][nt][2] + bv);
        s.w = f2bf(acc[mt][nt][3] + bv);
        *(short4*)&vrow[ssb + mt * 16] = s;
      }
    } else {
      ushort_t* plane = qkvh + (size_t)which * PLANE;
      #pragma unroll
      for (int mt = 0; mt < 4; ++mt) {
        #pragma unroll
        for (int reg = 0; reg < 4; ++reg) {
          int row = bm + wm * 64 + mt * 16 + quad * 4 + reg;
          int bb = row >> 11, ss = row & (SS - 1);
          plane[((size_t)(bb * HH + head) * SS + ss) * DHD + d] =
              (ushort_t)f2bf(acc[mt][nt][reg] + bv);
        }
      }
    }
  }
}

// ---------------------------------------------------------------------------
// GEMM 2 (R2-verified): y = x + attnb @ W_out + b_out -> fp32 d_out
// ---------------------------------------------------------------------------
__global__ __launch_bounds__(256) void gemm_proj_mfma(
    const ushort_t* __restrict__ A, const ushort_t* __restrict__ Bt,
    const float* __restrict__ bias, const float* __restrict__ xres,
    float* __restrict__ Y) {
  GEMM_MAIN(A, Bt, DD)
  #pragma unroll
  for (int nt = 0; nt < 4; ++nt) {
    int col = bn + wn * 64 + nt * 16 + lane16;
    float bv = bias[col];
    #pragma unroll
    for (int mt = 0; mt < 4; ++mt) {
      #pragma unroll
      for (int reg = 0; reg < 4; ++reg) {
        int row = bm + wm * 64 + mt * 16 + quad * 4 + reg;
        Y[(size_t)row * DD + col] =
            acc[mt][nt][reg] + bv + xres[(size_t)row * DD + col];
      }
    }
  }
}

// ---------------------------------------------------------------------------
// bf16 MFMA flash attention: EXACT R12 body (58.9us verified; no spills at
// VGPR 64 + 32 acc). R13/R14/R15: ANY accumulator growth spills ~9MB to
// scratch. Do not grow state here. Bank-conflict 4.19M = intrinsic b128
// wave64 cost (4 cyc/read, m134) -- not a layout bug, not fixable.
// ---------------------------------------------------------------------------
__global__ __launch_bounds__(512, 4) void attn_mfma_kernel(
    const ushort_t* __restrict__ qh, const ushort_t* __restrict__ kh,
    const ushort_t* __restrict__ vt, const u32* __restrict__ mbits,
    ushort_t* __restrict__ attn_out) {
  __shared__ __align__(16) ushort_t S[2][2][2][4096]; // [dbuf][K/V][khalf]

  const int tid = threadIdx.x;
  const int wave = tid >> 6, lane = tid & 63;
  const int l31 = lane & 31, hi = lane >> 5;

  const int bh = blockIdx.x & 31;          // b*16 + h
  const int qt = blockIdx.x >> 5;          // q tile of 128 (16 tiles)
  const int bbi = bh >> 4, hhi = bh & 15;
  const size_t head_base = (size_t)bh * SS * DHD;
  const int wq = wave & 3, khx = wave >> 2;
  const int q32 = qt * 128 + wq * 32;
  const int qrow = q32 + l31;              // this lane's q-row (scores + mask)

  // Q B-fragments, pre-scaled by log2(e)/sqrt(DH): qf[dk] holds row=qrow,
  // d = dk*16 + hi*8 .. +8  (32x32x16 B layout: col=lane&31, k=(lane>>5)*8+e)
  bf16x8 qf[4];
  {
    const float kScale = 0.125f * 1.44269504f;
    const ushort_t* qsrc = &qh[head_base + (size_t)qrow * DHD + hi * 8];
    #pragma unroll
    for (int dk = 0; dk < 4; ++dk) {
      bf16x8 r = *(const bf16x8*)&qsrc[dk * 16];
      #pragma unroll
      for (int e = 0; e < 8; ++e) {
        union { u32 u; float f; } c;
        c.u = ((u32)(ushort_t)r[e]) << 16;
        c.f *= kScale;
        r[e] = f2bf(c.f);
      }
      qf[dk] = r;
    }
  }

  f32x16 acc0, acc1;                       // O[q][d]: d = dt*32 + l31
  #pragma unroll
  for (int e = 0; e < 16; ++e) { acc0[e] = 0.f; acc1[e] = 0.f; }
  float lsum = 0.f;                        // sum of exps, all for q = qrow

  // mask words for this q-row, this k-half (32 u32 per half)
  const u32* mrow = mbits + ((size_t)(bbi * SS) + qrow) * 64 + khx * 32;

  // staging: 512 threads stage 4 tiles (K half0/1, V half0/1) of 512 chunks.
  // thread -> chunk (r = tid>>3, c = tid&7); source chunk pre-swizzled.
  const int sr = tid >> 3;
  const int scsrc = (tid & 7) ^ (sr & 7);
  const ushort_t* kst0 = kh + head_base + (size_t)sr * DHD + scsrc * 8;
  const ushort_t* vst0 = vt + head_base + (size_t)sr * SS + scsrc * 8;
  const int sdst = wave * 512;             // wave-uniform LDS base (shorts)

#define ATTN_STAGE(buf, t)                                                    \
  gload_lds16(kst0 + (size_t)(t) * 64 * DHD, &S[buf][0][0][sdst]);            \
  gload_lds16(kst0 + (size_t)(1024 + (t) * 64) * DHD, &S[buf][0][1][sdst]);   \
  gload_lds16(vst0 + (t) * 64, &S[buf][1][0][sdst]);                          \
  gload_lds16(vst0 + 1024 + (t) * 64, &S[buf][1][1][sdst]);

  ATTN_STAGE(0, 0);
  uint2 mcur = *(const uint2*)mrow;
  __syncthreads();

  const int NT = 16;                       // 1024 k per half / 64
  for (int t = 0; t < NT; ++t) {
    const int cur = t & 1;
    uint2 mnext = mcur;
    if (t + 1 < NT) {
      ATTN_STAGE(cur ^ 1, t + 1);
      mnext = *(const uint2*)&mrow[(t + 1) * 2];
    }

    const ushort_t* Kb = &S[cur][0][khx][0];
    const ushort_t* Vb = &S[cur][1][khx][0];

    // S^T = K.Q^T: two 32-k sub-tiles; C col = l31 = q, row = k pattern
    f32x16 s0, s1;
    #pragma unroll
    for (int e = 0; e < 16; ++e) { s0[e] = 0.f; s1[e] = 0.f; }
    #pragma unroll
    for (int dk = 0; dk < 4; ++dk) {
      const int c = 2 * dk + hi;
      const int r0 = l31;
      bf16x8 kf0 = *(const bf16x8*)&Kb[r0 * 64 + ((c ^ (r0 & 7)) * 8)];
      s0 = __builtin_amdgcn_mfma_f32_32x32x16_bf16(kf0, qf[dk], s0, 0, 0, 0);
      const int r1 = 32 + l31;
      bf16x8 kf1 = *(const bf16x8*)&Kb[r1 * 64 + ((c ^ (r1 & 7)) * 8)];
      s1 = __builtin_amdgcn_mfma_f32_32x32x16_bf16(kf1, qf[dk], s1, 0, 0, 0);
    }

    // per K=16 slice: mask+exp (k = 8g + 4hi + r), pack, permlane-swap to
    // build PV A-frag (row=q=l31, k=(hi)*8+e), then PV MFMA
    #pragma unroll
    for (int ks16 = 0; ks16 < 4; ++ks16) {
      const int ksub = ks16 >> 1;          // which 32-k sub-tile
      const int g0 = (ks16 & 1) * 2;       // first 8-k block within sub-tile
      const f32x16 sv = ksub ? s1 : s0;
      const u32 w32 = ksub ? mcur.y : mcur.x;
      const u32 na = w32 >> (g0 * 8 + hi * 4);
      const u32 nb = w32 >> (g0 * 8 + 8 + hi * 4);
      float e0 = (na & 1u) ? 0.f : ex2(sv[g0 * 4 + 0]);
      float e1 = (na & 2u) ? 0.f : ex2(sv[g0 * 4 + 1]);
      float e2 = (na & 4u) ? 0.f : ex2(sv[g0 * 4 + 2]);
      float e3 = (na & 8u) ? 0.f : ex2(sv[g0 * 4 + 3]);
      float f0 = (nb & 1u) ? 0.f : ex2(sv[g0 * 4 + 4]);
      float f1 = (nb & 2u) ? 0.f : ex2(sv[g0 * 4 + 5]);
      float f2 = (nb & 4u) ? 0.f : ex2(sv[g0 * 4 + 6]);
      float f3 = (nb & 8u) ? 0.f : ex2(sv[g0 * 4 + 7]);
      lsum += ((e0 + e1) + (e2 + e3)) + ((f0 + f1) + (f2 + f3));
      u32 a0 = pkbf(e0, e1), a1 = pkbf(e2, e3);
      u32 b0 = pkbf(f0, f1), b1 = pkbf(f2, f3);
      // swap: a' = {a_lo | b_lo from partner}, b' = {a_hi from partner | b_hi}
      asm("v_permlane32_swap_b32 %0, %1" : "+v"(a0), "+v"(b0));
      asm("v_permlane32_swap_b32 %0, %1" : "+v"(a1), "+v"(b1));
      union { u32 w[4]; bf16x8 v; } pfu;
      pfu.w[0] = a0; pfu.w[1] = a1; pfu.w[2] = b0; pfu.w[3] = b1;
      {
        const int rv0 = l31;
        const int cv = 2 * ks16 + hi;
        bf16x8 vf0 = *(const bf16x8*)&Vb[rv0 * 64 + ((cv ^ (rv0 & 7)) * 8)];
        acc0 = __builtin_amdgcn_mfma_f32_32x32x16_bf16(pfu.v, vf0, acc0, 0, 0, 0);
        const int rv1 = 32 + l31;
        bf16x8 vf1 = *(const bf16x8*)&Vb[rv1 * 64 + ((cv ^ (rv1 & 7)) * 8)];
        acc1 = __builtin_amdgcn_mfma_f32_32x32x16_bf16(pfu.v, vf1, acc1, 0, 0, 0);
      }
    }

    mcur = mnext;
    __syncthreads();   // drains gloads; separates buffer reuse
  }
#undef ATTN_STAGE

  // ---- merge k-halves + l transpose through LDS (staging bufs are dead) ----
  // stride 33 f32: bank = (lane*33 + e) % 32 = (lane + e) % 32 -> conflict-free
  float* mbuf = (float*)&S[0][0][0][0];            // [4][64][33] f32 = 33792 B
  float* lbuf = mbuf + 4 * 64 * 33;                // [khW][wq][hiW][32] = 2 KB
  lbuf[((khx * 4 + wq) * 2 + hi) * 32 + l31] = lsum;
  if (khx == 1) {
    float* dst = mbuf + (size_t)(wq * 64 + lane) * 33;
    #pragma unroll
    for (int e = 0; e < 16; ++e) { dst[e] = acc0[e]; dst[16 + e] = acc1[e]; }
  }
  __syncthreads();
  if (khx == 0) {
    const float* src = mbuf + (size_t)(wq * 64 + lane) * 33;
    #pragma unroll
    for (int e = 0; e < 16; ++e) { acc0[e] += src[e]; acc1[e] += src[16 + e]; }
    #pragma unroll
    for (int reg = 0; reg < 16; ++reg) {
      const int kq = (reg & 3) + 8 * (reg >> 2) + 4 * hi;   // q offset in 32
      float lq = lbuf[((0 * 4 + wq) * 2 + 0) * 32 + kq]
               + lbuf[((0 * 4 + wq) * 2 + 1) * 32 + kq]
               + lbuf[((1 * 4 + wq) * 2 + 0) * 32 + kq]
               + lbuf[((1 * 4 + wq) * 2 + 1) * 32 + kq];
      const float inv = 1.0f / lq;
      ushort_t* orow = &attn_out[((size_t)(bbi * SS) + q32 + kq) * DD
                                 + hhi * DHD];
      orow[l31] = (ushort_t)f2bf(acc0[reg] * inv);
      orow[32 + l31] = (ushort_t)f2bf(acc1[reg] * inv);
    }
  }
}

// ---------------------------------------------------------------------------
// in-place LayerNorm over D=1024 per row
// ---------------------------------------------------------------------------
__global__ __launch_bounds__(256) void ln_kernel(
    float* __restrict__ Y, const float* __restrict__ g,
    const float* __restrict__ bta) {
  const int r = blockIdx.x;
  const int tid = threadIdx.x;
  float4 v = *(const float4*)&Y[(size_t)r * DD + tid * 4];
  float sum = v.x + v.y + v.z + v.w;
  float sq = v.x * v.x + v.y * v.y + v.z * v.z + v.w * v.w;
  #pragma unroll
  for (int off = 32; off; off >>= 1) {
    sum += __shfl_down(sum, off);
    sq += __shfl_down(sq, off);
  }
  __shared__ float ps[4], pq[4];
  __shared__ float mu_s, rs_s;
  const int wave = tid >> 6;
  if ((tid & 63) == 0) { ps[wave] = sum; pq[wave] = sq; }
  __syncthreads();
  if (tid == 0) {
    float s = ps[0] + ps[1] + ps[2] + ps[3];
    float qq = pq[0] + pq[1] + pq[2] + pq[3];
    float mu = s * (1.0f / DD);
    float var = qq * (1.0f / DD) - mu * mu;
    mu_s = mu;
    rs_s = rsqrtf(var + LN_EPS);
  }
  __syncthreads();
  const float mu = mu_s, rs = rs_s;
  float4 g4 = *(const float4*)&g[tid * 4];
  float4 b4 = *(const float4*)&bta[tid * 4];
  float4 ov;
  ov.x = (v.x - mu) * rs * g4.x + b4.x;
  ov.y = (v.y - mu) * rs * g4.y + b4.y;
  ov.z = (v.z - mu) * rs * g4.z + b4.z;
  ov.w = (v.w - mu) * rs * g4.w + b4.w;
  *(float4*)&Y[(size_t)r * DD + tid * 4] = ov;
}

// ---------------------------------------------------------------------------
extern "C" void kernel_launch(void* const* d_in, const int* in_sizes, int n_in,
                              void* d_out, int out_size, void* d_ws, size_t ws_size,
                              hipStream_t stream) {
  const float* x      = (const float*)d_in[0];
  const float* W_attn = (const float*)d_in[1];
  const float* b_attn = (const float*)d_in[2];
  const float* W_out  = (const float*)d_in[3];
  const float* b_out  = (const float*)d_in[4];
  const float* ln_g   = (const float*)d_in[5];
  const float* ln_b   = (const float*)d_in[6];
  const int*   mask   = (const int*)d_in[7];
  float* out = (float*)d_out;
  ushort_t* ws = (ushort_t*)d_ws;

  ushort_t* xb    = ws;                                   // [4096][1024] bf16
  ushort_t* watt  = xb + (size_t)BB * SS * DD;            // [3072][1024] W_attn^T
  ushort_t* wot   = watt + (size_t)N3 * DD;               // [1024][1024] W_out^T
  ushort_t* qh    = wot + (size_t)DD * DD;                // [B,H,S,DH] q plane
  ushort_t* kh    = qh + (size_t)PLANE;                   // [B,H,S,DH] k plane
  ushort_t* vtb   = kh + (size_t)PLANE;                   // [B,H,DH,S] V^T
  ushort_t* attnb = vtb + (size_t)PLANE;                  // [4096][1024]
  u32* mbits      = (u32*)(attnb + (size_t)BB * SS * DD); // 1 MB packed mask

  // 0) fused prep: x cast + both weight transposes + mask bit-pack
  prep_kernel<<<dim3(PREP_TOTAL_B), 256, 0, stream>>>(
      x, xb, W_attn, watt, W_out, wot, mask, mbits);

  // 1) QKV projection (bf16 MFMA) -> q/k head-major, V^T short4 in-register
  gemm_qkv_mfma<<<dim3(N3 / 128, (BB * SS) / 128), 256, 0, stream>>>(
      xb, watt, b_attn, qh, vtb);
  // 2) bf16 MFMA flash attention (exact R12 body)
  attn_mfma_kernel<<<dim3(BB * HH * (SS / 128)), 512, 0, stream>>>(
      qh, kh, vtb, mbits, attnb);
  // 3) out projection + bias + residual (bf16 MFMA)
  gemm_proj_mfma<<<dim3(DD / 128, (BB * SS) / 128), 256, 0, stream>>>(
      attnb, wot, b_out, x, out);
  // 4) in-place LayerNorm
  ln_kernel<<<dim3(BB * SS), 256, 0, stream>>>(out, ln_g, ln_b);
}

// Round 13
// 227.553 us; speedup vs baseline: 1.0718x; 1.0054x over previous
//
#include <hip/hip_runtime.h>
#include <math.h>

#define BB 2
#define SS 2048
#define DD 1024
#define HH 16
#define DHD 64
#define N3 3072
#define LN_EPS 1e-5f

#define PLANE (BB*HH*SS*DHD)   // 4194304 elements per q/k/v plane

typedef __attribute__((ext_vector_type(8))) short bf16x8;
typedef __attribute__((ext_vector_type(4))) float f32x4;
typedef __attribute__((ext_vector_type(16))) float f32x16;
typedef unsigned int u32;
typedef unsigned short ushort_t;

// fp32 -> bf16 round-to-nearest-even (finite inputs only)
static __device__ __forceinline__ short f2bf(float f) {
  union { float f; unsigned u; } a;
  a.f = f;
  unsigned r = a.u + 0x7fffu + ((a.u >> 16) & 1u);
  return (short)(r >> 16);
}

static __device__ __forceinline__ u32 fbits(float f) {
  union { float f; u32 u; } a; a.f = f; return a.u;
}

// raw v_exp_f32 (2^x); avoids libm exp2f range-fixup bloat
static __device__ __forceinline__ float ex2(float x) {
  float r;
  asm("v_exp_f32 %0, %1" : "=v"(r) : "v"(x));
  return r;
}

// pack two f32 -> one u32 of 2 bf16 (round-half-up), lo at low 16
static __device__ __forceinline__ u32 pkbf(float lo, float hi) {
  return __builtin_amdgcn_perm(fbits(hi) + 0x8000u, fbits(lo) + 0x8000u,
                               0x07060302u);
}

// async global->LDS, 16 bytes per lane; lds dest = base + lane*16 (wave-uniform base)
static __device__ __forceinline__ void gload_lds16(const void* g, void* l) {
  __builtin_amdgcn_global_load_lds(
      (const __attribute__((address_space(1))) u32*)g,
      (__attribute__((address_space(3))) u32*)l, 16, 0, 0);
}

// ---------------------------------------------------------------------------
// Fused prep kernel (R17-verified): x cast + weight transposes + vectorized
// mask bit-pack (int4 loads, shfl_xor tree; word w = elems 32w..32w+31).
// ---------------------------------------------------------------------------
#define PREP_CONV_B   2048
#define PREP_TA_B     768     // (3072/64)*(1024/64)
#define PREP_TO_B     256     // (1024/64)*(1024/64)
#define PREP_PACK_B   8192    // BB*SS*SS/(256*4)
#define PREP_TOTAL_B  (PREP_CONV_B + PREP_TA_B + PREP_TO_B + PREP_PACK_B)

__global__ __launch_bounds__(256) void prep_kernel(
    const float* __restrict__ x, ushort_t* __restrict__ xb,
    const float* __restrict__ Wa, ushort_t* __restrict__ watt,
    const float* __restrict__ Wo, ushort_t* __restrict__ wot,
    const int* __restrict__ mask, u32* __restrict__ bits) {
  __shared__ float tile[64][65];
  const int tid = threadIdx.x;
  const int bid = blockIdx.x;

  if (bid < PREP_CONV_B) {
    int i = (bid * 256 + tid) * 8;
    float4 a = *(const float4*)&x[i];
    float4 b = *(const float4*)&x[i + 4];
    short s[8] = {f2bf(a.x), f2bf(a.y), f2bf(a.z), f2bf(a.w),
                  f2bf(b.x), f2bf(b.y), f2bf(b.z), f2bf(b.w)};
    *(bf16x8*)&xb[i] = *(bf16x8*)s;
    return;
  }
  if (bid < PREP_CONV_B + PREP_TA_B + PREP_TO_B) {
    const float* W; ushort_t* Wt; int K, N, nb, kb;
    if (bid < PREP_CONV_B + PREP_TA_B) {
      int idx = bid - PREP_CONV_B;
      W = Wa; Wt = watt; K = DD; N = N3;
      nb = (idx % 48) * 64; kb = (idx / 48) * 64;
    } else {
      int idx = bid - PREP_CONV_B - PREP_TA_B;
      W = Wo; Wt = wot; K = DD; N = DD;
      nb = (idx % 16) * 64; kb = (idx / 16) * 64;
    }
    #pragma unroll
    for (int i = 0; i < 4; ++i) {
      int idx = tid + i * 256;
      int r = idx >> 4, c = (idx & 15) * 4;
      float4 v = *(const float4*)&W[(size_t)(kb + r) * N + nb + c];
      tile[r][c] = v.x; tile[r][c + 1] = v.y;
      tile[r][c + 2] = v.z; tile[r][c + 3] = v.w;
    }
    __syncthreads();
    #pragma unroll
    for (int i = 0; i < 4; ++i) {
      int idx = tid + i * 256;
      int n = idx >> 4, k = (idx & 15) * 4;
      short4 s;
      s.x = f2bf(tile[k][n]); s.y = f2bf(tile[k + 1][n]);
      s.z = f2bf(tile[k + 2][n]); s.w = f2bf(tile[k + 3][n]);
      *(short4*)&Wt[(size_t)(nb + n) * K + kb + k] = s;
    }
    return;
  }
  {
    // mask bit-pack: thread handles 4 consecutive ints (16B load)
    size_t idx = (size_t)(bid - PREP_CONV_B - PREP_TA_B - PREP_TO_B) * 256 + tid;
    size_t g4 = idx * 4;                       // element base, %4==0
    int4 m = *(const int4*)&mask[g4];
    u32 v = (m.x != 0 ? 1u : 0u) | (m.y != 0 ? 2u : 0u)
          | (m.z != 0 ? 4u : 0u) | (m.w != 0 ? 8u : 0u);
    v |= (u32)__shfl_xor((int)v, 1) << 4;      // even lanes: 8 bits
    v |= (u32)__shfl_xor((int)v, 2) << 8;      // lanes %4==0: 16 bits
    v |= (u32)__shfl_xor((int)v, 4) << 16;     // lanes %8==0: 32 bits
    if ((tid & 7) == 0) bits[g4 >> 5] = v;     // word w = elems 32w..32w+31
  }
}

// ===========================================================================
// m97-style bf16 MFMA GEMM core (R2-verified): C[128x128] = A[128xK]*Bt^T
// Default block order (R16 lesson: NBX%8==0 already gives B-col->XCD L2
// affinity; swizzling broke it).
// ===========================================================================
#define GEMM_MAIN(Aptr, Btptr, Kdim)                                          \
  __shared__ ushort_t As[128 * 64];                                           \
  __shared__ ushort_t Bs[128 * 64];                                           \
  const int tid = threadIdx.x;                                                \
  const int wave = tid >> 6, lane = tid & 63;                                 \
  const int lane16 = lane & 15, quad = lane >> 4;                             \
  const int wm = wave & 1, wn = wave >> 1;                                    \
  const int bm = blockIdx.y * 128, bn = blockIdx.x * 128;                     \
  const int srow = lane >> 3;                                                 \
  const int sg = (lane & 7) ^ srow;                                           \
  f32x4 acc[4][4];                                                            \
  _Pragma("unroll") for (int i = 0; i < 4; ++i)                               \
    _Pragma("unroll") for (int j = 0; j < 4; ++j)                             \
      acc[i][j] = (f32x4){0.f, 0.f, 0.f, 0.f};                                \
  const ushort_t* agp[4];                                                     \
  const ushort_t* bgp[4];                                                     \
  _Pragma("unroll") for (int i = 0; i < 4; ++i) {                             \
    int seg = wave * 4 + i;                                                   \
    int r = seg * 8 + srow;                                                   \
    agp[i] = Aptr + (size_t)(bm + r) * Kdim + sg * 8;                         \
    bgp[i] = Btptr + (size_t)(bn + r) * Kdim + sg * 8;                        \
  }                                                                           \
  for (int k0 = 0; k0 < Kdim; k0 += 64) {                                     \
    _Pragma("unroll") for (int i = 0; i < 4; ++i) {                           \
      int seg = wave * 4 + i;                                                 \
      gload_lds16(agp[i] + k0, &As[seg * 512]);                               \
      gload_lds16(bgp[i] + k0, &Bs[seg * 512]);                               \
    }                                                                         \
    __syncthreads();                                                          \
    _Pragma("unroll") for (int ks = 0; ks < 2; ++ks) {                        \
      bf16x8 af[4], bfr[4];                                                   \
      _Pragma("unroll") for (int mt = 0; mt < 4; ++mt) {                      \
        int ra = wm * 64 + mt * 16 + lane16;                                  \
        int kc = ks * 4 + quad;                                               \
        af[mt] = *(const bf16x8*)&As[ra * 64 + ((kc ^ (ra & 7)) * 8)];        \
      }                                                                       \
      _Pragma("unroll") for (int nt = 0; nt < 4; ++nt) {                      \
        int rb = wn * 64 + nt * 16 + lane16;                                  \
        int kc = ks * 4 + quad;                                               \
        bfr[nt] = *(const bf16x8*)&Bs[rb * 64 + ((kc ^ (rb & 7)) * 8)];       \
      }                                                                       \
      _Pragma("unroll") for (int mt = 0; mt < 4; ++mt)                        \
        _Pragma("unroll") for (int nt = 0; nt < 4; ++nt)                      \
          acc[mt][nt] = __builtin_amdgcn_mfma_f32_16x16x32_bf16(              \
              af[mt], bfr[nt], acc[mt][nt], 0, 0, 0);                         \
    }                                                                         \
    __syncthreads();                                                          \
  }

// ---------------------------------------------------------------------------
// GEMM 1 (R19-verified): qkv -> bf16 head-major q/k [B,H,S,DH]; V^T
// [B,H,DH,S] via in-register short4 stores (reg=0..3 = 4 consecutive ss).
// ---------------------------------------------------------------------------
__global__ __launch_bounds__(256) void gemm_qkv_mfma(
    const ushort_t* __restrict__ A, const ushort_t* __restrict__ Bt,
    const float* __restrict__ bias, ushort_t* __restrict__ qkvh,
    ushort_t* __restrict__ vtb) {
  GEMM_MAIN(A, Bt, DD)
  #pragma unroll
  for (int nt = 0; nt < 4; ++nt) {
    int col = bn + wn * 64 + nt * 16 + lane16;
    int which = col >> 10, hcol = col & 1023;
    int head = hcol >> 6, d = hcol & 63;
    float bv = bias[col];
    if (which == 2) {
      // rows bm..bm+127 never cross a 2048 boundary (128 | 2048)
      const int bb = bm >> 11;
      const int ssb = (bm & 2047) + wm * 64 + quad * 4;
      ushort_t* vrow = vtb + ((size_t)(bb * HH + head) * DHD + d) * SS;
      #pragma unroll
      for (int mt = 0; mt < 4; ++mt) {
        short4 s;
        s.x = f2bf(acc[mt][nt][0] + bv);
        s.y = f2bf(acc[mt][nt][1] + bv);
        s.z = f2bf(acc[mt][nt][2] + bv);
        s.w = f2bf(acc[mt][nt][3] + bv);
        *(short4*)&vrow[ssb + mt * 16] = s;
      }
    } else {
      ushort_t* plane = qkvh + (size_t)which * PLANE;
      #pragma unroll
      for (int mt = 0; mt < 4; ++mt) {
        #pragma unroll
        for (int reg = 0; reg < 4; ++reg) {
          int row = bm + wm * 64 + mt * 16 + quad * 4 + reg;
          int bb = row >> 11, ss = row & (SS - 1);
          plane[((size_t)(bb * HH + head) * SS + ss) * DHD + d] =
              (ushort_t)f2bf(acc[mt][nt][reg] + bv);
        }
      }
    }
  }
}

// ---------------------------------------------------------------------------
// GEMM 2 (R2-verified): y = x + attnb @ W_out + b_out -> fp32 d_out
// ---------------------------------------------------------------------------
__global__ __launch_bounds__(256) void gemm_proj_mfma(
    const ushort_t* __restrict__ A, const ushort_t* __restrict__ Bt,
    const float* __restrict__ bias, const float* __restrict__ xres,
    float* __restrict__ Y) {
  GEMM_MAIN(A, Bt, DD)
  #pragma unroll
  for (int nt = 0; nt < 4; ++nt) {
    int col = bn + wn * 64 + nt * 16 + lane16;
    float bv = bias[col];
    #pragma unroll
    for (int mt = 0; mt < 4; ++mt) {
      #pragma unroll
      for (int reg = 0; reg < 4; ++reg) {
        int row = bm + wm * 64 + mt * 16 + quad * 4 + reg;
        Y[(size_t)row * DD + col] =
            acc[mt][nt][reg] + bv + xres[(size_t)row * DD + col];
      }
    }
  }
}

// ---------------------------------------------------------------------------
// bf16 MFMA flash attention: EXACT R12 body (58.9us verified; no spills at
// VGPR 64 + 32 acc). R13/R14/R15: ANY accumulator growth spills ~9MB to
// scratch. Do not grow state here. Bank-conflict 4.19M = intrinsic b128
// wave64 cost (4 cyc/read, m134) -- not a layout bug, not fixable.
// ---------------------------------------------------------------------------
__global__ __launch_bounds__(512, 4) void attn_mfma_kernel(
    const ushort_t* __restrict__ qh, const ushort_t* __restrict__ kh,
    const ushort_t* __restrict__ vt, const u32* __restrict__ mbits,
    ushort_t* __restrict__ attn_out) {
  __shared__ __align__(16) ushort_t S[2][2][2][4096]; // [dbuf][K/V][khalf]

  const int tid = threadIdx.x;
  const int wave = tid >> 6, lane = tid & 63;
  const int l31 = lane & 31, hi = lane >> 5;

  const int bh = blockIdx.x & 31;          // b*16 + h
  const int qt = blockIdx.x >> 5;          // q tile of 128 (16 tiles)
  const int bbi = bh >> 4, hhi = bh & 15;
  const size_t head_base = (size_t)bh * SS * DHD;
  const int wq = wave & 3, khx = wave >> 2;
  const int q32 = qt * 128 + wq * 32;
  const int qrow = q32 + l31;              // this lane's q-row (scores + mask)

  // Q B-fragments, pre-scaled by log2(e)/sqrt(DH): qf[dk] holds row=qrow,
  // d = dk*16 + hi*8 .. +8  (32x32x16 B layout: col=lane&31, k=(lane>>5)*8+e)
  bf16x8 qf[4];
  {
    const float kScale = 0.125f * 1.44269504f;
    const ushort_t* qsrc = &qh[head_base + (size_t)qrow * DHD + hi * 8];
    #pragma unroll
    for (int dk = 0; dk < 4; ++dk) {
      bf16x8 r = *(const bf16x8*)&qsrc[dk * 16];
      #pragma unroll
      for (int e = 0; e < 8; ++e) {
        union { u32 u; float f; } c;
        c.u = ((u32)(ushort_t)r[e]) << 16;
        c.f *= kScale;
        r[e] = f2bf(c.f);
      }
      qf[dk] = r;
    }
  }

  f32x16 acc0, acc1;                       // O[q][d]: d = dt*32 + l31
  #pragma unroll
  for (int e = 0; e < 16; ++e) { acc0[e] = 0.f; acc1[e] = 0.f; }
  float lsum = 0.f;                        // sum of exps, all for q = qrow

  // mask words for this q-row, this k-half (32 u32 per half)
  const u32* mrow = mbits + ((size_t)(bbi * SS) + qrow) * 64 + khx * 32;

  // staging: 512 threads stage 4 tiles (K half0/1, V half0/1) of 512 chunks.
  // thread -> chunk (r = tid>>3, c = tid&7); source chunk pre-swizzled.
  const int sr = tid >> 3;
  const int scsrc = (tid & 7) ^ (sr & 7);
  const ushort_t* kst0 = kh + head_base + (size_t)sr * DHD + scsrc * 8;
  const ushort_t* vst0 = vt + head_base + (size_t)sr * SS + scsrc * 8;
  const int sdst = wave * 512;             // wave-uniform LDS base (shorts)

#define ATTN_STAGE(buf, t)                                                    \
  gload_lds16(kst0 + (size_t)(t) * 64 * DHD, &S[buf][0][0][sdst]);            \
  gload_lds16(kst0 + (size_t)(1024 + (t) * 64) * DHD, &S[buf][0][1][sdst]);   \
  gload_lds16(vst0 + (t) * 64, &S[buf][1][0][sdst]);                          \
  gload_lds16(vst0 + 1024 + (t) * 64, &S[buf][1][1][sdst]);

  ATTN_STAGE(0, 0);
  uint2 mcur = *(const uint2*)mrow;
  __syncthreads();

  const int NT = 16;                       // 1024 k per half / 64
  for (int t = 0; t < NT; ++t) {
    const int cur = t & 1;
    uint2 mnext = mcur;
    if (t + 1 < NT) {
      ATTN_STAGE(cur ^ 1, t + 1);
      mnext = *(const uint2*)&mrow[(t + 1) * 2];
    }

    const ushort_t* Kb = &S[cur][0][khx][0];
    const ushort_t* Vb = &S[cur][1][khx][0];

    // S^T = K.Q^T: two 32-k sub-tiles; C col = l31 = q, row = k pattern
    f32x16 s0, s1;
    #pragma unroll
    for (int e = 0; e < 16; ++e) { s0[e] = 0.f; s1[e] = 0.f; }
    #pragma unroll
    for (int dk = 0; dk < 4; ++dk) {
      const int c = 2 * dk + hi;
      const int r0 = l31;
      bf16x8 kf0 = *(const bf16x8*)&Kb[r0 * 64 + ((c ^ (r0 & 7)) * 8)];
      s0 = __builtin_amdgcn_mfma_f32_32x32x16_bf16(kf0, qf[dk], s0, 0, 0, 0);
      const int r1 = 32 + l31;
      bf16x8 kf1 = *(const bf16x8*)&Kb[r1 * 64 + ((c ^ (r1 & 7)) * 8)];
      s1 = __builtin_amdgcn_mfma_f32_32x32x16_bf16(kf1, qf[dk], s1, 0, 0, 0);
    }

    // per K=16 slice: mask+exp (k = 8g + 4hi + r), pack, permlane-swap to
    // build PV A-frag (row=q=l31, k=(hi)*8+e), then PV MFMA
    #pragma unroll
    for (int ks16 = 0; ks16 < 4; ++ks16) {
      const int ksub = ks16 >> 1;          // which 32-k sub-tile
      const int g0 = (ks16 & 1) * 2;       // first 8-k block within sub-tile
      const f32x16 sv = ksub ? s1 : s0;
      const u32 w32 = ksub ? mcur.y : mcur.x;
      const u32 na = w32 >> (g0 * 8 + hi * 4);
      const u32 nb = w32 >> (g0 * 8 + 8 + hi * 4);
      float e0 = (na & 1u) ? 0.f : ex2(sv[g0 * 4 + 0]);
      float e1 = (na & 2u) ? 0.f : ex2(sv[g0 * 4 + 1]);
      float e2 = (na & 4u) ? 0.f : ex2(sv[g0 * 4 + 2]);
      float e3 = (na & 8u) ? 0.f : ex2(sv[g0 * 4 + 3]);
      float f0 = (nb & 1u) ? 0.f : ex2(sv[g0 * 4 + 4]);
      float f1 = (nb & 2u) ? 0.f : ex2(sv[g0 * 4 + 5]);
      float f2 = (nb & 4u) ? 0.f : ex2(sv[g0 * 4 + 6]);
      float f3 = (nb & 8u) ? 0.f : ex2(sv[g0 * 4 + 7]);
      lsum += ((e0 + e1) + (e2 + e3)) + ((f0 + f1) + (f2 + f3));
      u32 a0 = pkbf(e0, e1), a1 = pkbf(e2, e3);
      u32 b0 = pkbf(f0, f1), b1 = pkbf(f2, f3);
      // swap: a' = {a_lo | b_lo from partner}, b' = {a_hi from partner | b_hi}
      asm("v_permlane32_swap_b32 %0, %1" : "+v"(a0), "+v"(b0));
      asm("v_permlane32_swap_b32 %0, %1" : "+v"(a1), "+v"(b1));
      union { u32 w[4]; bf16x8 v; } pfu;
      pfu.w[0] = a0; pfu.w[1] = a1; pfu.w[2] = b0; pfu.w[3] = b1;
      {
        const int rv0 = l31;
        const int cv = 2 * ks16 + hi;
        bf16x8 vf0 = *(const bf16x8*)&Vb[rv0 * 64 + ((cv ^ (rv0 & 7)) * 8)];
        acc0 = __builtin_amdgcn_mfma_f32_32x32x16_bf16(pfu.v, vf0, acc0, 0, 0, 0);
        const int rv1 = 32 + l31;
        bf16x8 vf1 = *(const bf16x8*)&Vb[rv1 * 64 + ((cv ^ (rv1 & 7)) * 8)];
        acc1 = __builtin_amdgcn_mfma_f32_32x32x16_bf16(pfu.v, vf1, acc1, 0, 0, 0);
      }
    }

    mcur = mnext;
    __syncthreads();   // drains gloads; separates buffer reuse
  }
#undef ATTN_STAGE

  // ---- merge k-halves + l transpose through LDS (staging bufs are dead) ----
  // stride 33 f32: bank = (lane*33 + e) % 32 = (lane + e) % 32 -> conflict-free
  float* mbuf = (float*)&S[0][0][0][0];            // [4][64][33] f32 = 33792 B
  float* lbuf = mbuf + 4 * 64 * 33;                // [khW][wq][hiW][32] = 2 KB
  lbuf[((khx * 4 + wq) * 2 + hi) * 32 + l31] = lsum;
  if (khx == 1) {
    float* dst = mbuf + (size_t)(wq * 64 + lane) * 33;
    #pragma unroll
    for (int e = 0; e < 16; ++e) { dst[e] = acc0[e]; dst[16 + e] = acc1[e]; }
  }
  __syncthreads();
  if (khx == 0) {
    const float* src = mbuf + (size_t)(wq * 64 + lane) * 33;
    #pragma unroll
    for (int e = 0; e < 16; ++e) { acc0[e] += src[e]; acc1[e] += src[16 + e]; }
    #pragma unroll
    for (int reg = 0; reg < 16; ++reg) {
      const int kq = (reg & 3) + 8 * (reg >> 2) + 4 * hi;   // q offset in 32
      float lq = lbuf[((0 * 4 + wq) * 2 + 0) * 32 + kq]
               + lbuf[((0 * 4 + wq) * 2 + 1) * 32 + kq]
               + lbuf[((1 * 4 + wq) * 2 + 0) * 32 + kq]
               + lbuf[((1 * 4 + wq) * 2 + 1) * 32 + kq];
      const float inv = 1.0f / lq;
      ushort_t* orow = &attn_out[((size_t)(bbi * SS) + q32 + kq) * DD
                                 + hhi * DHD];
      orow[l31] = (ushort_t)f2bf(acc0[reg] * inv);
      orow[32 + l31] = (ushort_t)f2bf(acc1[reg] * inv);
    }
  }
}

// ---------------------------------------------------------------------------
// in-place LayerNorm over D=1024, R20: one wave per row (4 rows/block).
// 16 floats/lane cover the row; reduction pure-shfl (no LDS, no barriers).
// Loads/stores stay 1KB-contiguous per wave instruction.
// ---------------------------------------------------------------------------
__global__ __launch_bounds__(256) void ln_kernel(
    float* __restrict__ Y, const float* __restrict__ g,
    const float* __restrict__ bta) {
  const int wave = threadIdx.x >> 6, lane = threadIdx.x & 63;
  const int r = blockIdx.x * 4 + wave;
  float* yrow = &Y[(size_t)r * DD];
  const int c0 = lane * 4;
  float4 v[4];
  float sum = 0.f, sq = 0.f;
  #pragma unroll
  for (int i = 0; i < 4; ++i) {
    v[i] = *(const float4*)&yrow[i * 256 + c0];
    sum += (v[i].x + v[i].y) + (v[i].z + v[i].w);
    sq += (v[i].x * v[i].x + v[i].y * v[i].y)
        + (v[i].z * v[i].z + v[i].w * v[i].w);
  }
  #pragma unroll
  for (int off = 32; off; off >>= 1) {
    sum += __shfl_down(sum, off);
    sq += __shfl_down(sq, off);
  }
  sum = __shfl(sum, 0);
  sq = __shfl(sq, 0);
  const float mu = sum * (1.0f / DD);
  const float var = sq * (1.0f / DD) - mu * mu;
  const float rs = rsqrtf(var + LN_EPS);
  #pragma unroll
  for (int i = 0; i < 4; ++i) {
    float4 g4 = *(const float4*)&g[i * 256 + c0];
    float4 b4 = *(const float4*)&bta[i * 256 + c0];
    float4 ov;
    ov.x = (v[i].x - mu) * rs * g4.x + b4.x;
    ov.y = (v[i].y - mu) * rs * g4.y + b4.y;
    ov.z = (v[i].z - mu) * rs * g4.z + b4.z;
    ov.w = (v[i].w - mu) * rs * g4.w + b4.w;
    *(float4*)&yrow[i * 256 + c0] = ov;
  }
}

// ---------------------------------------------------------------------------
extern "C" void kernel_launch(void* const* d_in, const int* in_sizes, int n_in,
                              void* d_out, int out_size, void* d_ws, size_t ws_size,
                              hipStream_t stream) {
  const float* x      = (const float*)d_in[0];
  const float* W_attn = (const float*)d_in[1];
  const float* b_attn = (const float*)d_in[2];
  const float* W_out  = (const float*)d_in[3];
  const float* b_out  = (const float*)d_in[4];
  const float* ln_g   = (const float*)d_in[5];
  const float* ln_b   = (const float*)d_in[6];
  const int*   mask   = (const int*)d_in[7];
  float* out = (float*)d_out;
  ushort_t* ws = (ushort_t*)d_ws;

  ushort_t* xb    = ws;                                   // [4096][1024] bf16
  ushort_t* watt  = xb + (size_t)BB * SS * DD;            // [3072][1024] W_attn^T
  ushort_t* wot   = watt + (size_t)N3 * DD;               // [1024][1024] W_out^T
  ushort_t* qh    = wot + (size_t)DD * DD;                // [B,H,S,DH] q plane
  ushort_t* kh    = qh + (size_t)PLANE;                   // [B,H,S,DH] k plane
  ushort_t* vtb   = kh + (size_t)PLANE;                   // [B,H,DH,S] V^T
  ushort_t* attnb = vtb + (size_t)PLANE;                  // [4096][1024]
  u32* mbits      = (u32*)(attnb + (size_t)BB * SS * DD); // 1 MB packed mask

  // 0) fused prep: x cast + both weight transposes + mask bit-pack
  prep_kernel<<<dim3(PREP_TOTAL_B), 256, 0, stream>>>(
      x, xb, W_attn, watt, W_out, wot, mask, mbits);

  // 1) QKV projection (bf16 MFMA) -> q/k head-major, V^T short4 in-register
  gemm_qkv_mfma<<<dim3(N3 / 128, (BB * SS) / 128), 256, 0, stream>>>(
      xb, watt, b_attn, qh, vtb);
  // 2) bf16 MFMA flash attention (exact R12 body)
  attn_mfma_kernel<<<dim3(BB * HH * (SS / 128)), 512, 0, stream>>>(
      qh, kh, vtb, mbits, attnb);
  // 3) out projection + bias + residual (bf16 MFMA)
  gemm_proj_mfma<<<dim3(DD / 128, (BB * SS) / 128), 256, 0, stream>>>(
      attnb, wot, b_out, x, out);
  // 4) in-place LayerNorm (wave-per-row, barrier-free)
  ln_kernel<<<dim3(BB * SS / 4), 256, 0, stream>>>(out, ln_g, ln_b);
}